// Round 8
// baseline (215.537 us; speedup 1.0000x reference)
//
#include <hip/hip_runtime.h>
#include <hip/hip_bf16.h>
#include <stdint.h>

// Problem constants
#define B_   1024
#define L_   50
#define D_   128
#define NV_  8
#define NH_  16
#define KFC  1824   // NV*D + NH*L

typedef __bf16 bf16x8 __attribute__((ext_vector_type(8)));
typedef float  f32x4  __attribute__((ext_vector_type(4)));

static __device__ __forceinline__ bf16x8 as_bf16x8(uint4 u) {
  return __builtin_bit_cast(bf16x8, u);
}

// round-to-nearest-even f32 -> bf16 bits
static __device__ __forceinline__ unsigned short f2b(float x) {
  unsigned u = __float_as_uint(x);
  return (unsigned short)((u + 0x7FFFu + ((u >> 16) & 1u)) >> 16);
}

// ---- workspace layout (bytes) ----
// [0, OV)          : o buffer, B x 1824 f32 (o_v | o_h), memset 0 each launch
// [E3OFF, +E3SZ)   : E bf16, [ks(4)][bg(64)][row(56)][16 b x 64B]
//                    rows 0..49 data, row 50 zeros, rows 51..55 never-read pad
// [W2OFF, +W2SZ)   : repacked conv weights: [pair p=T(i)+j][ks(4)][64 lanes x 16B]
#define OV_BYTES  ((size_t)B_ * KFC * 4)                  //  7,471,104
#define E3OFF     (OV_BYTES)
#define E3_BG     57344                                   // 56 rows x 1024
#define E3_KS     ((size_t)64 * E3_BG)                    //  3,670,016
#define E3SZ      ((size_t)4 * E3_KS)                     // 14,680,064
#define W2OFF     (E3OFF + E3SZ)
#define W2SZ      ((size_t)1275 * 4096)                   //  5,222,400
#define NEED_FULL (W2OFF + W2SZ)                          // 27,373,568

// ======================= kernel P: P_u copy -> out[:, 128:256]
__global__ void ck_kP(const int* __restrict__ uids, const float* __restrict__ uemb,
                      float* __restrict__ out) {
  int b = blockIdx.x, d = threadIdx.x;  // 128 threads
  out[(size_t)b * 256 + 128 + d] = uemb[(size_t)uids[b] * D_ + d];
}

// degenerate fallback (only if ws too small)
__global__ void ck_kZ(float* __restrict__ out) {
  int i = blockIdx.x * 256 + threadIdx.x;
  int b = i >> 7, d = i & 127;
  out[(size_t)b * 256 + d] = 0.f;
}

// ======================= kernel AB: gather E (f32 LDS) -> {bf16 E3 global, o_v}
__global__ void ck_kAB(const int* __restrict__ item_seq, const float* __restrict__ item_emb,
                       const float* __restrict__ vf, char* __restrict__ ws) {
  int b = blockIdx.x, tid = threadIdx.x;
  __shared__ float E[L_][D_];
  __shared__ float VF[L_][NV_];
  __shared__ int sidx[L_];
  if (tid < L_) sidx[tid] = item_seq[b * L_ + tid];
  for (int c = tid; c < L_ * NV_; c += 256) VF[c / NV_][c % NV_] = vf[c];
  __syncthreads();
  for (int c = tid; c < 1600; c += 256) {   // 50 rows x 32 float4
    int l = c >> 5, ch = c & 31;
    *(float4*)&E[l][ch * 4] = *(const float4*)(item_emb + (size_t)sidx[l] * D_ + ch * 4);
  }
  __syncthreads();
  // (a) bf16 E3, row-major [row][b][64B]
  char* eg = ws + E3OFF + (size_t)(b >> 4) * E3_BG + (b & 15) * 64;
  #pragma unroll
  for (int it = 0; it < 4; ++it) {
    int c = it * 256 + tid;                 // 0..1023; need 816
    if (c < 816) {
      int ks = c / 204, rem = c - ks * 204;
      uint4 v = make_uint4(0, 0, 0, 0);
      int row, gq;
      if (rem < 200) {
        row = rem >> 2; gq = rem & 3;
        float4 f0 = *(const float4*)&E[row][ks * 32 + gq * 8];
        float4 f1 = *(const float4*)&E[row][ks * 32 + gq * 8 + 4];
        v.x = f2b(f0.x) | ((unsigned)f2b(f0.y) << 16);
        v.y = f2b(f0.z) | ((unsigned)f2b(f0.w) << 16);
        v.z = f2b(f1.x) | ((unsigned)f2b(f1.y) << 16);
        v.w = f2b(f1.z) | ((unsigned)f2b(f1.w) << 16);
      } else {
        row = 50; gq = rem - 200;           // zero pad row
      }
      *(uint4*)(eg + (size_t)ks * E3_KS + row * 1024 + gq * 16) = v;
    }
  }
  // (b) o_v
  int d = tid & 127, half = tid >> 7;
  float acc[4] = {0.f, 0.f, 0.f, 0.f};
  for (int l = 0; l < L_; ++l) {
    float e = E[l][d];
    #pragma unroll
    for (int vv = 0; vv < 4; ++vv) acc[vv] += e * VF[l][half * 4 + vv];
  }
  float* o = (float*)ws + (size_t)b * KFC;
  #pragma unroll
  for (int vv = 0; vv < 4; ++vv) o[(half * 4 + vv) * D_ + d] = acc[vv];
}

// ======================= kernel W2: repack hconv_w -> B-frag-ready bf16
__global__ void ck_kW2(const float* __restrict__ hw, char* __restrict__ ws) {
  int p = blockIdx.x, tid = threadIdx.x;     // 1275 blocks x 256
  int ks = tid >> 6, l = tid & 63;
  int n = l & 15, gq = l >> 4;
  int i = (int)((sqrtf(8.0f * (float)p + 1.0f) - 1.0f) * 0.5f);
  while ((i + 1) * (i + 2) / 2 <= p) ++i;
  while (i * (i + 1) / 2 > p) --i;
  int j = p - i * (i + 1) / 2;
  const float* src = hw + ((size_t)(i * 16 + n) * 50 + j) * 128 + ks * 32 + gq * 8;
  float4 f0 = *(const float4*)(src);
  float4 f1 = *(const float4*)(src + 4);
  uint4 v;
  v.x = f2b(f0.x) | ((unsigned)f2b(f0.y) << 16);
  v.y = f2b(f0.z) | ((unsigned)f2b(f0.w) << 16);
  v.z = f2b(f1.x) | ((unsigned)f2b(f1.y) << 16);
  v.w = f2b(f1.z) | ((unsigned)f2b(f1.w) << 16);
  *(uint4*)(ws + W2OFF + (size_t)p * 4096 + tid * 16) = v;
}

// ======================= kernel C7: double-buffered LDS + win[16] batch prefetch
#define MFMA_BF16 __builtin_amdgcn_mfma_f32_16x16x32_bf16
#define NWIN   182
#define NPH    24                       // 6 rounds x 4 ks
#define EBUF   57344
#define SB_OFF (2 * EBUF)               // wcost 182 ints (pad 736B)
#define SC_OFF (2 * EBUF + 736)         // sched 32 slots x 6 rounds = 192 ints
#define LDS_TOT (2 * EBUF + 736 + 768)  // 116192

// one macro-step: prefetch rows j0+8..15, then 8 j-steps of NT4 MFMAs
template<int P, int NT4>
__device__ __forceinline__ void mstep7(const char* buf, const char* bp0, int aoff,
    int t0, int jb, int i, bf16x8 (&win)[16], uint4 (&breg)[8], f32x4 (&acc)[8]) {
  const int j0 = jb + P;
  #pragma unroll
  for (int q = 0; q < 8; ++q) {
    int s = t0 + j0 + 8 + q; s = s > 50 ? 50 : s;
    win[(P + 8 + q) & 15] = as_bf16x8(*(const uint4*)(buf + s * 1024 + aoff));
  }
  #pragma unroll
  for (int u = 0; u < 8; ++u) {
    int j = j0 + u;
    if (j <= i) {
      bf16x8 bfr = as_bf16x8(breg[u]);
      #pragma unroll
      for (int tt = 0; tt < NT4; ++tt)
        acc[tt] = MFMA_BF16(win[(P + u + tt) & 15], bfr, acc[tt], 0, 0, 0);
      if (j + 8 <= i) breg[u] = *(const uint4*)(bp0 + (size_t)(j + 8) * 4096);
    }
  }
}

template<int NT4>
__device__ __forceinline__ void proc7(const char* buf, const char* bp0, int i, int t0,
    int aoff, f32x4 (&acc)[8]) {
  bf16x8 win[16];
  #pragma unroll
  for (int q = 0; q < 8; ++q) {
    int s = t0 + q; s = s > 50 ? 50 : s;
    win[q] = as_bf16x8(*(const uint4*)(buf + s * 1024 + aoff));
  }
  uint4 breg[8];
  #pragma unroll
  for (int u = 0; u < 8; ++u)
    breg[u] = *(const uint4*)(bp0 + (size_t)(u <= i ? u : 0) * 4096);
  for (int jb = 0; jb <= i; jb += 16) {
    mstep7<0, NT4>(buf, bp0, aoff, t0, jb, i, win, breg, acc);
    if (jb + 8 <= i)
      mstep7<8, NT4>(buf, bp0, aoff, t0, jb, i, win, breg, acc);
  }
}

__device__ __forceinline__ void run7(const char* buf, const char* W2, int ks, int enc,
    f32x4 (&acc)[8], int aoff, int lane) {
  int i = enc & 0xff, t0 = (enc >> 8) & 0xff, nt4 = (enc >> 24) & 0xff;
  const char* bp0 = W2 + (size_t)(i * (i + 1) / 2) * 4096 + ks * 1024 + lane * 16;
  if (nt4 == 4) proc7<4>(buf, bp0, i, t0, aoff, acc);
  else          proc7<8>(buf, bp0, i, t0, aoff, acc);
}

__device__ __forceinline__ void epi7(float* o, const float* hb, int b0,
    int enc, f32x4 (&acc)[8], int lane) {
  int i = enc & 0xff, nt = (enc >> 16) & 0xff;
  int r = lane & 15, gq = lane >> 4;
  float bias = hb[i * 16 + r];
  #pragma unroll
  for (int e = 0; e < 4; ++e) {
    float m = 0.f;
    #pragma unroll
    for (int tt = 0; tt < 8; ++tt)
      if (tt < nt) m = fmaxf(m, fmaxf(acc[tt][e] + bias, 0.f));
    atomicMax((unsigned*)&o[(size_t)(b0 + gq * 4 + e) * KFC + 1024 + i * 16 + r],
              __float_as_uint(m));
  }
}

__launch_bounds__(512, 2)
__global__ void ck_kC7(const float* __restrict__ hconv_b, char* __restrict__ ws) {
  __shared__ char lds[LDS_TOT];
  int* wcost = (int*)(lds + SB_OFF);
  int* sched = (int*)(lds + SC_OFF);   // 32 slots x 6 rounds
  int tid = threadIdx.x;
  int wv = tid >> 6, lane = tid & 63;
  int r = lane & 15, gq = lane >> 4;
  int g = (int)blockIdx.x;             // bgroup; all 4 blocks of g on XCD g%8
  int slot = (int)blockIdx.y * 8 + wv; // 0..31
  int aoff = r * 64 + gq * 16;

  const char* EG = ws + E3OFF + (size_t)g * E3_BG;
  const char* W2 = ws + W2OFF;
  float* o = (float*)ws;

  // issue phase-0 stage loads early (hide under schedule build)
  uint4 sreg[7];
  #pragma unroll
  for (int it = 0; it < 7; ++it)
    sreg[it] = *(const uint4*)(EG + (size_t)(it * 512 + tid) * 16);

  // ---- snake schedule: 182 windows ranked by cost, dealt to 32 slots x 6 rounds
  if (tid < 192) sched[tid] = -1;
  int myenc = -1;
  if (tid < NWIN) {
    int idx = tid, i, nw = 1;
    for (i = 0; i < 50; ++i) {
      nw = (57 - i) >> 3;              // ceil((50-i)/8)
      if (idx < nw) break;
      idx -= nw;
    }
    int ntb = 50 - i - 8 * (nw - 1);
    int nt = idx ? 8 : ntb;
    int t0 = idx ? ntb + 8 * (idx - 1) : 0;
    int nt4 = (nt + 3) & ~3;
    myenc = i | (t0 << 8) | (nt << 16) | (nt4 << 24);
    wcost[tid] = (((i + 1) * nt4) << 8) + tid;
  }
  __syncthreads();
  if (tid < NWIN) {
    int c = wcost[tid], rank = 0;
    for (int u = 0; u < NWIN; ++u) rank += (wcost[u] > c) ? 1 : 0;
    int rnd = rank >> 5, pos = rank & 31;
    int sl = (rnd & 1) ? (31 - pos) : pos;
    sched[sl * 6 + rnd] = myenc;
  }
  __syncthreads();
  // commit phase-0 stage
  #pragma unroll
  for (int it = 0; it < 7; ++it)
    *(uint4*)(lds + (size_t)(it * 512 + tid) * 16) = sreg[it];
  __syncthreads();

  f32x4 acc[8];
  int enc = -1;
  for (int p = 0; p < NPH; ++p) {
    int rd = p >> 2, ks = p & 3;
    if (p + 1 < NPH) {                 // issue-early loads for next phase
      const char* src = EG + (size_t)((p + 1) & 3) * E3_KS;
      #pragma unroll
      for (int it = 0; it < 7; ++it)
        sreg[it] = *(const uint4*)(src + (size_t)(it * 512 + tid) * 16);
    }
    if (ks == 0) {
      enc = sched[slot * 6 + rd];
      #pragma unroll
      for (int t = 0; t < 8; ++t) {
        acc[t][0] = 0.f; acc[t][1] = 0.f; acc[t][2] = 0.f; acc[t][3] = 0.f;
      }
    }
    const char* buf = lds + (size_t)(p & 1) * EBUF;
    if (enc >= 0) run7(buf, W2, ks, enc, acc, aoff, lane);
    if (enc >= 0 && ks == 3) epi7(o, hconv_b, g * 16, enc, acc, lane);
    if (p + 1 < NPH) {                 // write next phase into other buffer
      char* dbuf = lds + (size_t)((p + 1) & 1) * EBUF;
      #pragma unroll
      for (int it = 0; it < 7; ++it)
        *(uint4*)(dbuf + (size_t)(it * 512 + tid) * 16) = sreg[it];
    }
    __syncthreads();
  }
}

// ======================= kernel D: FC (full K, 2 ksteps/phase) + bias + relu
__launch_bounds__(256)
__global__ void ck_kD(const float* __restrict__ fc_w, const float* __restrict__ fc_b,
                      const char* __restrict__ ws, float* __restrict__ out) {
  __shared__ char ldsD[10240];  // A0@0 A1@4096 (4KB each); B0@8192 B1@9216 (1KB each)
  int b0 = blockIdx.x * 64, n0 = blockIdx.y * 16;
  int tid = threadIdx.x, w = tid >> 6, lane = tid & 63, r = lane & 15, gq = lane >> 4;
  const float* o = (const float*)ws;

  f32x4 acc; acc[0] = 0.f; acc[1] = 0.f; acc[2] = 0.f; acc[3] = 0.f;

  int rl = tid >> 2, ch = tid & 3;
  const float* asrc = o + (size_t)(b0 + rl) * KFC + ch * 8;
  int kk = tid >> 3, nn = tid & 7;

  float4 fa[4]; float fb[4];
  fa[0] = *(const float4*)(asrc);
  fa[1] = *(const float4*)(asrc + 4);
  fa[2] = *(const float4*)(asrc + 32);
  fa[3] = *(const float4*)(asrc + 36);
  fb[0] = fc_w[(size_t)kk * D_ + n0 + nn];
  fb[1] = fc_w[(size_t)kk * D_ + n0 + nn + 8];
  fb[2] = fc_w[(size_t)(32 + kk) * D_ + n0 + nn];
  fb[3] = fc_w[(size_t)(32 + kk) * D_ + n0 + nn + 8];

  int arow_off = rl * 64 + ((ch ^ (rl & 3)) << 4);
  int rloc = w * 16 + r;
  int ard = rloc * 64 + ((gq ^ (rloc & 3)) << 4);
  int brd = 8192 + r * 64 + ((gq ^ (r & 3)) << 4);
  int bw0 = 8192 + nn * 64 + (((kk >> 3) ^ (nn & 3)) << 4) + (kk & 7) * 2;
  int bw1 = 8192 + (nn + 8) * 64 + (((kk >> 3) ^ ((nn + 8) & 3)) << 4) + (kk & 7) * 2;

  for (int s = 0; s < 29; ++s) {
    int k1ok = (2 * s + 1) < 57;
    __syncthreads();
    #pragma unroll
    for (int sl = 0; sl < 2; ++sl) {
      uint4 v;
      v.x = f2b(fa[2*sl].x) | ((unsigned)f2b(fa[2*sl].y) << 16);
      v.y = f2b(fa[2*sl].z) | ((unsigned)f2b(fa[2*sl].w) << 16);
      v.z = f2b(fa[2*sl+1].x) | ((unsigned)f2b(fa[2*sl+1].y) << 16);
      v.w = f2b(fa[2*sl+1].z) | ((unsigned)f2b(fa[2*sl+1].w) << 16);
      *(uint4*)(ldsD + sl * 4096 + arow_off) = v;
      *(unsigned short*)(ldsD + sl * 1024 + bw0) = f2b(fb[2*sl]);
      *(unsigned short*)(ldsD + sl * 1024 + bw1) = f2b(fb[2*sl+1]);
    }
    __syncthreads();
    int kn0 = (2 * s + 2) * 32, kn1 = (2 * s + 3) * 32;
    if (kn0 < 1824) {
      fa[0] = *(const float4*)(asrc + kn0);
      fa[1] = *(const float4*)(asrc + kn0 + 4);
      fb[0] = fc_w[(size_t)(kn0 + kk) * D_ + n0 + nn];
      fb[1] = fc_w[(size_t)(kn0 + kk) * D_ + n0 + nn + 8];
    }
    if (kn1 < 1824) {
      fa[2] = *(const float4*)(asrc + kn1);
      fa[3] = *(const float4*)(asrc + kn1 + 4);
      fb[2] = fc_w[(size_t)(kn1 + kk) * D_ + n0 + nn];
      fb[3] = fc_w[(size_t)(kn1 + kk) * D_ + n0 + nn + 8];
    }
    bf16x8 a0  = as_bf16x8(*(const uint4*)(ldsD + ard));
    bf16x8 b0f = as_bf16x8(*(const uint4*)(ldsD + brd));
    acc = __builtin_amdgcn_mfma_f32_16x16x32_bf16(a0, b0f, acc, 0, 0, 0);
    if (k1ok) {
      bf16x8 a1  = as_bf16x8(*(const uint4*)(ldsD + 4096 + ard));
      bf16x8 b1f = as_bf16x8(*(const uint4*)(ldsD + 1024 + brd));
      acc = __builtin_amdgcn_mfma_f32_16x16x32_bf16(a1, b1f, acc, 0, 0, 0);
    }
  }

  float bias = fc_b[n0 + r];
  #pragma unroll
  for (int e = 0; e < 4; ++e) {
    int row = b0 + w * 16 + gq * 4 + e;
    out[(size_t)row * 256 + n0 + r] = fmaxf(acc[e] + bias, 0.f);
  }
}

extern "C" void kernel_launch(void* const* d_in, const int* in_sizes, int n_in,
                              void* d_out, int out_size, void* d_ws, size_t ws_size,
                              hipStream_t stream) {
  const int*   user_ids = (const int*)d_in[0];
  const int*   item_seq = (const int*)d_in[1];
  const float* user_emb = (const float*)d_in[2];
  const float* item_emb = (const float*)d_in[3];
  const float* vfilter  = (const float*)d_in[4];
  const float* hconv_w  = (const float*)d_in[5];
  const float* hconv_b  = (const float*)d_in[6];
  const float* fc_w     = (const float*)d_in[7];
  const float* fc_b     = (const float*)d_in[8];
  float* out = (float*)d_out;
  char*  ws  = (char*)d_ws;

  ck_kP<<<dim3(B_), dim3(128), 0, stream>>>(user_ids, user_emb, out);

  if (ws_size < NEED_FULL) {
    ck_kZ<<<dim3(512), dim3(256), 0, stream>>>(out);
    return;
  }

  hipMemsetAsync(ws, 0, OV_BYTES, stream);  // atomicMax identity (all outputs >= 0)

  ck_kAB<<<dim3(B_), dim3(256), 0, stream>>>(item_seq, item_emb, vfilter, ws);
  ck_kW2<<<dim3(1275), dim3(256), 0, stream>>>(hconv_w, ws);
  ck_kC7<<<dim3(64, 4), dim3(512), 0, stream>>>(hconv_b, ws);
  ck_kD<<<dim3(16, 8), dim3(256), 0, stream>>>(fc_w, fc_b, ws, out);
}

// Round 9
// 175.333 us; speedup vs baseline: 1.2293x; 1.2293x over previous
//
#include <hip/hip_runtime.h>
#include <hip/hip_bf16.h>
#include <stdint.h>

// Problem constants
#define B_   1024
#define L_   50
#define D_   128
#define NV_  8
#define NH_  16
#define KFC  1824   // NV*D + NH*L

typedef __bf16 bf16x8 __attribute__((ext_vector_type(8)));
typedef float  f32x4  __attribute__((ext_vector_type(4)));

static __device__ __forceinline__ bf16x8 as_bf16x8(uint4 u) {
  return __builtin_bit_cast(bf16x8, u);
}

// round-to-nearest-even f32 -> bf16 bits
static __device__ __forceinline__ unsigned short f2b(float x) {
  unsigned u = __float_as_uint(x);
  return (unsigned short)((u + 0x7FFFu + ((u >> 16) & 1u)) >> 16);
}

// ---- workspace layout (bytes) ----
// [0, OV)          : o buffer, B x 1824 f32 (o_v | o_h), memset 0 each launch
// [E3OFF, +E3SZ)   : E bf16, [ks(4)][bg(64)][row(51)][16 b x 64B] (row 50 = zeros)
// [W2OFF, +W2SZ)   : repacked conv weights: [pair p=T(i)+j][ks(4)][64 lanes x 16B]
// [CTR_OFF, +256)  : 64 per-bgroup work counters (memset 0 each launch)
#define OV_BYTES  ((size_t)B_ * KFC * 4)                  //  7,471,104
#define E3OFF     (OV_BYTES)
#define E3_BG     52224                                   // 51 rows x 1024
#define E3_KS     ((size_t)64 * E3_BG)                    //  3,342,336
#define E3SZ      ((size_t)4 * E3_KS)                     // 13,369,344
#define W2OFF     (E3OFF + E3SZ)
#define W2SZ      ((size_t)1275 * 4096)                   //  5,222,400
#define CTR_OFF   (W2OFF + W2SZ)
#define NEED_FULL (CTR_OFF + 256)                         // 26,063,104

// async global->LDS DMA, 16B per lane, wave-uniform LDS base + lane*16
#define GLD16(gsrc, ldst) __builtin_amdgcn_global_load_lds(                    \
    (const __attribute__((address_space(1))) void*)(gsrc),                     \
    (__attribute__((address_space(3))) void*)(ldst), 16, 0, 0)

// ======================= kernel P: P_u copy -> out[:, 128:256]
__global__ void ck_kP(const int* __restrict__ uids, const float* __restrict__ uemb,
                      float* __restrict__ out) {
  int b = blockIdx.x, d = threadIdx.x;  // 128 threads
  out[(size_t)b * 256 + 128 + d] = uemb[(size_t)uids[b] * D_ + d];
}

// degenerate fallback (only if ws too small)
__global__ void ck_kZ(float* __restrict__ out) {
  int i = blockIdx.x * 256 + threadIdx.x;
  int b = i >> 7, d = i & 127;
  out[(size_t)b * 256 + d] = 0.f;
}

// ======================= kernel AB: gather E (f32 LDS) -> {bf16 E3 global, o_v}
__global__ void ck_kAB(const int* __restrict__ item_seq, const float* __restrict__ item_emb,
                       const float* __restrict__ vf, char* __restrict__ ws) {
  int b = blockIdx.x, tid = threadIdx.x;
  __shared__ float E[L_][D_];
  __shared__ float VF[L_][NV_];
  __shared__ int sidx[L_];
  if (tid < L_) sidx[tid] = item_seq[b * L_ + tid];
  for (int c = tid; c < L_ * NV_; c += 256) VF[c / NV_][c % NV_] = vf[c];
  __syncthreads();
  for (int c = tid; c < 1600; c += 256) {   // 50 rows x 32 float4
    int l = c >> 5, ch = c & 31;
    *(float4*)&E[l][ch * 4] = *(const float4*)(item_emb + (size_t)sidx[l] * D_ + ch * 4);
  }
  __syncthreads();
  // (a) bf16 E3, row-major [row][b][64B]
  char* eg = ws + E3OFF + (size_t)(b >> 4) * E3_BG + (b & 15) * 64;
  #pragma unroll
  for (int it = 0; it < 4; ++it) {
    int c = it * 256 + tid;                 // 0..1023; need 816
    if (c < 816) {
      int ks = c / 204, rem = c - ks * 204;
      uint4 v = make_uint4(0, 0, 0, 0);
      int row, gq;
      if (rem < 200) {
        row = rem >> 2; gq = rem & 3;
        float4 f0 = *(const float4*)&E[row][ks * 32 + gq * 8];
        float4 f1 = *(const float4*)&E[row][ks * 32 + gq * 8 + 4];
        v.x = f2b(f0.x) | ((unsigned)f2b(f0.y) << 16);
        v.y = f2b(f0.z) | ((unsigned)f2b(f0.w) << 16);
        v.z = f2b(f1.x) | ((unsigned)f2b(f1.y) << 16);
        v.w = f2b(f1.z) | ((unsigned)f2b(f1.w) << 16);
      } else {
        row = 50; gq = rem - 200;           // zero pad row
      }
      *(uint4*)(eg + (size_t)ks * E3_KS + row * 1024 + gq * 16) = v;
    }
  }
  // (b) o_v
  int d = tid & 127, half = tid >> 7;
  float acc[4] = {0.f, 0.f, 0.f, 0.f};
  for (int l = 0; l < L_; ++l) {
    float e = E[l][d];
    #pragma unroll
    for (int vv = 0; vv < 4; ++vv) acc[vv] += e * VF[l][half * 4 + vv];
  }
  float* o = (float*)ws + (size_t)b * KFC;
  #pragma unroll
  for (int vv = 0; vv < 4; ++vv) o[(half * 4 + vv) * D_ + d] = acc[vv];
}

// ======================= kernel W2: repack hconv_w -> B-frag-ready bf16
__global__ void ck_kW2(const float* __restrict__ hw, char* __restrict__ ws) {
  int p = blockIdx.x, tid = threadIdx.x;     // 1275 blocks x 256
  int ks = tid >> 6, l = tid & 63;
  int n = l & 15, gq = l >> 4;
  int i = (int)((sqrtf(8.0f * (float)p + 1.0f) - 1.0f) * 0.5f);
  while ((i + 1) * (i + 2) / 2 <= p) ++i;
  while (i * (i + 1) / 2 > p) --i;
  int j = p - i * (i + 1) / 2;
  const float* src = hw + ((size_t)(i * 16 + n) * 50 + j) * 128 + ks * 32 + gq * 8;
  float4 f0 = *(const float4*)(src);
  float4 f1 = *(const float4*)(src + 4);
  uint4 v;
  v.x = f2b(f0.x) | ((unsigned)f2b(f0.y) << 16);
  v.y = f2b(f0.z) | ((unsigned)f2b(f0.w) << 16);
  v.z = f2b(f1.x) | ((unsigned)f2b(f1.y) << 16);
  v.w = f2b(f1.z) | ((unsigned)f2b(f1.w) << 16);
  *(uint4*)(ws + W2OFF + (size_t)p * 4096 + tid * 16) = v;
}

// ======================= kernel C8: M=batch convs, DMA staging, dynamic chunks
#define MFMA_BF16 __builtin_amdgcn_mfma_f32_16x16x32_bf16

// single code path: always 8 t-accumulators; invalid t's discarded in epilogue
__device__ __forceinline__ void proc8(const char* buf, const char* bp0,
    int i, int t0, f32x4 (&acc)[8], int aoff) {
  bf16x8 win[8];
  #pragma unroll
  for (int q = 0; q < 8; ++q) {
    int s = t0 + q; s = s > 50 ? 50 : s;
    win[q] = as_bf16x8(*(const uint4*)(buf + s * 1024 + aoff));
  }
  uint4 breg[8];
  #pragma unroll
  for (int u = 0; u < 8; ++u)
    breg[u] = *(const uint4*)(bp0 + (size_t)(u <= i ? u : 0) * 4096);

  for (int j0 = 0; j0 <= i; j0 += 8) {
    #pragma unroll
    for (int u = 0; u < 8; ++u) {
      int j = j0 + u;
      if (j <= i) {
        bf16x8 bfr = as_bf16x8(breg[u]);
        acc[0] = MFMA_BF16(win[u], bfr, acc[0], 0, 0, 0);
        acc[1] = MFMA_BF16(win[(u + 1) & 7], bfr, acc[1], 0, 0, 0);
        acc[2] = MFMA_BF16(win[(u + 2) & 7], bfr, acc[2], 0, 0, 0);
        acc[3] = MFMA_BF16(win[(u + 3) & 7], bfr, acc[3], 0, 0, 0);
        int sn = t0 + j + 8; sn = sn > 50 ? 50 : sn;   // row 50 = zero pad
        win[u] = as_bf16x8(*(const uint4*)(buf + sn * 1024 + aoff));  // slide
        acc[4] = MFMA_BF16(win[(u + 4) & 7], bfr, acc[4], 0, 0, 0);
        acc[5] = MFMA_BF16(win[(u + 5) & 7], bfr, acc[5], 0, 0, 0);
        acc[6] = MFMA_BF16(win[(u + 6) & 7], bfr, acc[6], 0, 0, 0);
        acc[7] = MFMA_BF16(win[(u + 7) & 7], bfr, acc[7], 0, 0, 0);
        if (j + 8 <= i) breg[u] = *(const uint4*)(bp0 + (size_t)(j + 8) * 4096);
      }
    }
  }
}

__launch_bounds__(512, 4)
__global__ void ck_kC8(const float* __restrict__ hconv_b, char* __restrict__ ws) {
  __shared__ __align__(16) char lds[E3_BG + 16];
  int* bcast = (int*)(lds + E3_BG);
  int tid = threadIdx.x;
  int wv = tid >> 6, lane = tid & 63;
  int r = lane & 15, gq = lane >> 4;
  int g = (int)blockIdx.x;             // bgroup; all 12 blocks of g on XCD g%8
  int aoff = r * 64 + gq * 16;

  const char* EG = ws + E3OFF + (size_t)g * E3_BG;
  const char* W2 = ws + W2OFF;
  unsigned* ctr = (unsigned*)(ws + CTR_OFF) + g;
  float* o = (float*)ws;

  for (;;) {
    if (tid == 0) bcast[0] = (int)atomicAdd(ctr, 8u);
    // stage ks=0 (prev round's reads all done at its last barrier)
    #pragma unroll
    for (int it = 0; it < 6; ++it)
      GLD16(EG + (size_t)(it * 512 + tid) * 16, lds + (it * 512 + wv * 64) * 16);
    if (wv < 3)
      GLD16(EG + (size_t)(3072 + tid) * 16, lds + (3072 + wv * 64) * 16);
    __syncthreads();                   // DMA landed (vmcnt drain) + bcast visible
    int base = bcast[0];
    if (base >= 182) break;

    // decode my window: widx in i-descending (= cost-descending) order
    int widx = base + wv;
    int i = -1, nt = 0, t0 = 0;
    int rem = widx;
    for (int ii = 49; ii >= 0; --ii) {
      int nw = (57 - ii) >> 3;         // ceil((50-ii)/8)
      if (rem < nw) {
        i = ii;
        int ntb = 50 - ii - 8 * (nw - 1);
        nt = rem ? 8 : ntb;
        t0 = rem ? ntb + 8 * (rem - 1) : 0;
        break;
      }
      rem -= nw;
    }                                  // widx >= 182 -> i stays -1 (idle wave)

    f32x4 acc[8];
    #pragma unroll
    for (int t = 0; t < 8; ++t) {
      acc[t][0] = 0.f; acc[t][1] = 0.f; acc[t][2] = 0.f; acc[t][3] = 0.f;
    }
    const char* bpb = W2 + (size_t)(i >= 0 ? i * (i + 1) / 2 : 0) * 4096 + lane * 16;

    for (int ks = 0; ks < 4; ++ks) {
      if (i >= 0) proc8(lds, bpb + ks * 1024, i, t0, acc, aoff);
      __syncthreads();                 // all reads of buf done
      if (ks < 3) {
        const char* src = EG + (size_t)(ks + 1) * E3_KS;
        #pragma unroll
        for (int it = 0; it < 6; ++it)
          GLD16(src + (size_t)(it * 512 + tid) * 16, lds + (it * 512 + wv * 64) * 16);
        if (wv < 3)
          GLD16(src + (size_t)(3072 + tid) * 16, lds + (3072 + wv * 64) * 16);
        __syncthreads();               // DMA landed
      }
    }

    if (i >= 0) {                      // epilogue: bias+relu+masked max, atomicMax
      int b0 = g * 16;
      float bias = hconv_b[i * 16 + r];
      #pragma unroll
      for (int e = 0; e < 4; ++e) {
        float m = 0.f;
        #pragma unroll
        for (int tt = 0; tt < 8; ++tt)
          if (tt < nt) m = fmaxf(m, fmaxf(acc[tt][e] + bias, 0.f));
        atomicMax((unsigned*)&o[(size_t)(b0 + gq * 4 + e) * KFC + 1024 + i * 16 + r],
                  __float_as_uint(m));
      }
    }
  }
}

// ======================= kernel D: FC (full K, 2 ksteps/phase) + bias + relu
__launch_bounds__(256)
__global__ void ck_kD(const float* __restrict__ fc_w, const float* __restrict__ fc_b,
                      const char* __restrict__ ws, float* __restrict__ out) {
  __shared__ char ldsD[10240];  // A0@0 A1@4096 (4KB each); B0@8192 B1@9216 (1KB each)
  int b0 = blockIdx.x * 64, n0 = blockIdx.y * 16;
  int tid = threadIdx.x, w = tid >> 6, lane = tid & 63, r = lane & 15, gq = lane >> 4;
  const float* o = (const float*)ws;

  f32x4 acc; acc[0] = 0.f; acc[1] = 0.f; acc[2] = 0.f; acc[3] = 0.f;

  int rl = tid >> 2, ch = tid & 3;
  const float* asrc = o + (size_t)(b0 + rl) * KFC + ch * 8;
  int kk = tid >> 3, nn = tid & 7;

  float4 fa[4]; float fb[4];
  fa[0] = *(const float4*)(asrc);
  fa[1] = *(const float4*)(asrc + 4);
  fa[2] = *(const float4*)(asrc + 32);
  fa[3] = *(const float4*)(asrc + 36);
  fb[0] = fc_w[(size_t)kk * D_ + n0 + nn];
  fb[1] = fc_w[(size_t)kk * D_ + n0 + nn + 8];
  fb[2] = fc_w[(size_t)(32 + kk) * D_ + n0 + nn];
  fb[3] = fc_w[(size_t)(32 + kk) * D_ + n0 + nn + 8];

  int arow_off = rl * 64 + ((ch ^ (rl & 3)) << 4);
  int rloc = w * 16 + r;
  int ard = rloc * 64 + ((gq ^ (rloc & 3)) << 4);
  int brd = 8192 + r * 64 + ((gq ^ (r & 3)) << 4);
  int bw0 = 8192 + nn * 64 + (((kk >> 3) ^ (nn & 3)) << 4) + (kk & 7) * 2;
  int bw1 = 8192 + (nn + 8) * 64 + (((kk >> 3) ^ ((nn + 8) & 3)) << 4) + (kk & 7) * 2;

  for (int s = 0; s < 29; ++s) {
    int k1ok = (2 * s + 1) < 57;
    __syncthreads();
    #pragma unroll
    for (int sl = 0; sl < 2; ++sl) {
      uint4 v;
      v.x = f2b(fa[2*sl].x) | ((unsigned)f2b(fa[2*sl].y) << 16);
      v.y = f2b(fa[2*sl].z) | ((unsigned)f2b(fa[2*sl].w) << 16);
      v.z = f2b(fa[2*sl+1].x) | ((unsigned)f2b(fa[2*sl+1].y) << 16);
      v.w = f2b(fa[2*sl+1].z) | ((unsigned)f2b(fa[2*sl+1].w) << 16);
      *(uint4*)(ldsD + sl * 4096 + arow_off) = v;
      *(unsigned short*)(ldsD + sl * 1024 + bw0) = f2b(fb[2*sl]);
      *(unsigned short*)(ldsD + sl * 1024 + bw1) = f2b(fb[2*sl+1]);
    }
    __syncthreads();
    int kn0 = (2 * s + 2) * 32, kn1 = (2 * s + 3) * 32;
    if (kn0 < 1824) {
      fa[0] = *(const float4*)(asrc + kn0);
      fa[1] = *(const float4*)(asrc + kn0 + 4);
      fb[0] = fc_w[(size_t)(kn0 + kk) * D_ + n0 + nn];
      fb[1] = fc_w[(size_t)(kn0 + kk) * D_ + n0 + nn + 8];
    }
    if (kn1 < 1824) {
      fa[2] = *(const float4*)(asrc + kn1);
      fa[3] = *(const float4*)(asrc + kn1 + 4);
      fb[2] = fc_w[(size_t)(kn1 + kk) * D_ + n0 + nn];
      fb[3] = fc_w[(size_t)(kn1 + kk) * D_ + n0 + nn + 8];
    }
    bf16x8 a0  = as_bf16x8(*(const uint4*)(ldsD + ard));
    bf16x8 b0f = as_bf16x8(*(const uint4*)(ldsD + brd));
    acc = __builtin_amdgcn_mfma_f32_16x16x32_bf16(a0, b0f, acc, 0, 0, 0);
    if (k1ok) {
      bf16x8 a1  = as_bf16x8(*(const uint4*)(ldsD + 4096 + ard));
      bf16x8 b1f = as_bf16x8(*(const uint4*)(ldsD + 1024 + brd));
      acc = __builtin_amdgcn_mfma_f32_16x16x32_bf16(a1, b1f, acc, 0, 0, 0);
    }
  }

  float bias = fc_b[n0 + r];
  #pragma unroll
  for (int e = 0; e < 4; ++e) {
    int row = b0 + w * 16 + gq * 4 + e;
    out[(size_t)row * 256 + n0 + r] = fmaxf(acc[e] + bias, 0.f);
  }
}

extern "C" void kernel_launch(void* const* d_in, const int* in_sizes, int n_in,
                              void* d_out, int out_size, void* d_ws, size_t ws_size,
                              hipStream_t stream) {
  const int*   user_ids = (const int*)d_in[0];
  const int*   item_seq = (const int*)d_in[1];
  const float* user_emb = (const float*)d_in[2];
  const float* item_emb = (const float*)d_in[3];
  const float* vfilter  = (const float*)d_in[4];
  const float* hconv_w  = (const float*)d_in[5];
  const float* hconv_b  = (const float*)d_in[6];
  const float* fc_w     = (const float*)d_in[7];
  const float* fc_b     = (const float*)d_in[8];
  float* out = (float*)d_out;
  char*  ws  = (char*)d_ws;

  ck_kP<<<dim3(B_), dim3(128), 0, stream>>>(user_ids, user_emb, out);

  if (ws_size < NEED_FULL) {
    ck_kZ<<<dim3(512), dim3(256), 0, stream>>>(out);
    return;
  }

  hipMemsetAsync(ws, 0, OV_BYTES, stream);        // atomicMax identity
  hipMemsetAsync(ws + CTR_OFF, 0, 256, stream);   // work counters

  ck_kAB<<<dim3(B_), dim3(256), 0, stream>>>(item_seq, item_emb, vfilter, ws);
  ck_kW2<<<dim3(1275), dim3(256), 0, stream>>>(hconv_w, ws);
  ck_kC8<<<dim3(64, 12), dim3(512), 0, stream>>>(hconv_b, ws);
  ck_kD<<<dim3(16, 8), dim3(256), 0, stream>>>(fc_w, fc_b, ws, out);
}